// Round 10
// baseline (143.939 us; speedup 1.0000x reference)
//
#include <hip/hip_runtime.h>
#include <hip/hip_bf16.h>

// SemanticDecoder: mean = b@Wmu+bmu; s = b@Wsig+bsig; var = s*s;
// sample = mean + |s|*eps.  B=65536, K=64, D=300. f32 in/out.
// Outputs concatenated: [sample, mean, var], each B*D.
//
// R10: ALL global I/O at 16 B/lane. Unified theory from R1-R9: every fused
// variant used 4 B/lane stores + eps loads -> capped at ~2.2-2.7 TB/s
// (fillBuffer/m13 prove 16B/lane = 6.3-7 TB/s; G13's 2.5x). Compute stays
// thread-per-column (pinned f16 weights, uniform b loads), results packed
// (mean,s) f16x2 into a 19.2 KB LDS tile; writeout phase streams eps in and
// sample/mean/var out as LINEAR float4 (300 = 75 quads/row => quad index is
// linear over B*D; LDS dword addr = quad index, conflict-free b128 reads).

#define B_ROWS 65536
#define K_DIM 64
#define D_DIM 300
#define ROWS_PER_BLOCK 16
#define THREADS 320
#define QPR 75                       // float4-quads per row
#define QPB (ROWS_PER_BLOCK * QPR)   // 1200 quads per block

typedef __fp16 half2v __attribute__((ext_vector_type(2)));

__device__ __forceinline__ float dot2h(half2v a, half2v b, float c) {
#if __has_builtin(__builtin_amdgcn_fdot2)
    return __builtin_amdgcn_fdot2(a, b, c, false);
#else
    return fmaf((float)a[0], (float)b[0], fmaf((float)a[1], (float)b[1], c));
#endif
}
__device__ __forceinline__ half2v h2(unsigned int u) {
    return __builtin_bit_cast(half2v, u);
}
__device__ __forceinline__ unsigned int pkd(float a, float b) {
    return __builtin_bit_cast(unsigned int, __builtin_amdgcn_cvt_pkrtz(a, b));
}

// ---- pack b[65536][64] f32 -> f16 in d_ws (16B/lane in and out) ----------
__global__ __launch_bounds__(256) void pack_b_kernel(
    const float* __restrict__ b, __fp16* __restrict__ bh)
{
    const size_t N8 = (size_t)B_ROWS * K_DIM / 8;   // 524288
    const size_t i = (size_t)blockIdx.x * blockDim.x + threadIdx.x;
    if (i >= N8) return;
    const float4* s = reinterpret_cast<const float4*>(b) + 2 * i;
    const float4 x = s[0], y = s[1];
    uint4 o;
    o.x = pkd(x.x, x.y);
    o.y = pkd(x.z, x.w);
    o.z = pkd(y.x, y.y);
    o.w = pkd(y.z, y.w);
    reinterpret_cast<uint4*>(bh)[i] = o;
}

// ---- main kernel (PACKED=1: b from f16 d_ws; 0: f32 b, cvt in-loop) ------
template<int PACKED>
__global__ __launch_bounds__(THREADS, 2) void sem_dec_kernel(
    const float* __restrict__ b,
    const __fp16* __restrict__ bh,
    const float* __restrict__ Wmu,
    const float* __restrict__ bmu,
    const float* __restrict__ Wsig,
    const float* __restrict__ bsig,
    const float* __restrict__ eps,
    float* __restrict__ out)
{
    __shared__ unsigned int lds_ms[QPB * 4];   // 4800 dwords = 19.2 KB

    const int tid  = threadIdx.x;
    const int row0 = blockIdx.x * ROWS_PER_BLOCK;

    // ================= compute phase: thread-per-column =================
    if (tid < D_DIM) {
        const int d = tid;
        // weight columns -> 64 packed-f16 dwords, pinned in VGPRs
        unsigned int wmd[32], wsd[32];
        #pragma unroll
        for (int k2 = 0; k2 < 32; ++k2) {
            wmd[k2] = pkd(Wmu[(size_t)(2 * k2) * D_DIM + d],
                          Wmu[(size_t)(2 * k2 + 1) * D_DIM + d]);
            wsd[k2] = pkd(Wsig[(size_t)(2 * k2) * D_DIM + d],
                          Wsig[(size_t)(2 * k2 + 1) * D_DIM + d]);
        }
        float bm = bmu[d];
        float bs = bsig[d];
        #pragma unroll
        for (int i = 0; i < 32; ++i) {
            asm volatile("" : "+v"(wmd[i]));
            asm volatile("" : "+v"(wsd[i]));
        }
        asm volatile("" : "+v"(bm));
        asm volatile("" : "+v"(bs));

        #pragma unroll 2
        for (int r = 0; r < ROWS_PER_BLOCK; ++r) {
            uint4 q[8];
            if (PACKED) {
                const uint4* bq = reinterpret_cast<const uint4*>(
                    bh + (size_t)(row0 + r) * K_DIM);
                #pragma unroll
                for (int j = 0; j < 8; ++j) q[j] = bq[j];  // uniform 16B
            } else {
                const float4* bf = reinterpret_cast<const float4*>(
                    b + (size_t)(row0 + r) * K_DIM);
                #pragma unroll
                for (int j = 0; j < 8; ++j) {
                    const float4 x = bf[2 * j], y = bf[2 * j + 1];
                    q[j].x = pkd(x.x, x.y);
                    q[j].y = pkd(x.z, x.w);
                    q[j].z = pkd(y.x, y.y);
                    q[j].w = pkd(y.z, y.w);
                }
            }
            float am0 = 0.f, am1 = 0.f, as0 = 0.f, as1 = 0.f;
            #pragma unroll
            for (int kk = 0; kk < 8; ++kk) {
                const half2v q0 = h2(q[kk].x), q1 = h2(q[kk].y);
                const half2v q2 = h2(q[kk].z), q3 = h2(q[kk].w);
                am0 = dot2h(q0, h2(wmd[4*kk+0]), am0);
                am1 = dot2h(q1, h2(wmd[4*kk+1]), am1);
                as0 = dot2h(q0, h2(wsd[4*kk+0]), as0);
                as1 = dot2h(q1, h2(wsd[4*kk+1]), as1);
                am0 = dot2h(q2, h2(wmd[4*kk+2]), am0);
                am1 = dot2h(q3, h2(wmd[4*kk+3]), am1);
                as0 = dot2h(q2, h2(wsd[4*kk+2]), as0);
                as1 = dot2h(q3, h2(wsd[4*kk+3]), as1);
            }
            const float mean = am0 + am1 + bm;
            const float s    = as0 + as1 + bs;
            lds_ms[r * D_DIM + d] = pkd(mean, s);  // (mean,s) f16x2
        }
    }
    __syncthreads();

    // ================= writeout phase: linear float4 streams ==============
    if (tid < 300) {
        const size_t BD  = (size_t)B_ROWS * D_DIM;
        const size_t gq0 = (size_t)row0 * QPR;     // block's first quad
        const float4* eps4  = reinterpret_cast<const float4*>(eps);
        float4* samp4 = reinterpret_cast<float4*>(out);
        float4* mean4 = reinterpret_cast<float4*>(out + BD);
        float4* var4  = reinterpret_cast<float4*>(out + 2 * BD);
        #pragma unroll
        for (int ph = 0; ph < 4; ++ph) {
            const int q = ph * 300 + tid;          // 0..1199, linear
            const uint4 ms = reinterpret_cast<const uint4*>(lds_ms)[q];
            const float4 e = eps4[gq0 + q];
            const half2v h0 = h2(ms.x), h1 = h2(ms.y);
            const half2v h2_ = h2(ms.z), h3 = h2(ms.w);
            float4 mv, sv;
            mv.x = (float)h0[0];  sv.x = (float)h0[1];
            mv.y = (float)h1[0];  sv.y = (float)h1[1];
            mv.z = (float)h2_[0]; sv.z = (float)h2_[1];
            mv.w = (float)h3[0];  sv.w = (float)h3[1];
            float4 sm, vr;
            sm.x = fmaf(fabsf(sv.x), e.x, mv.x);  vr.x = sv.x * sv.x;
            sm.y = fmaf(fabsf(sv.y), e.y, mv.y);  vr.y = sv.y * sv.y;
            sm.z = fmaf(fabsf(sv.z), e.z, mv.z);  vr.z = sv.z * sv.z;
            sm.w = fmaf(fabsf(sv.w), e.w, mv.w);  vr.w = sv.w * sv.w;
            samp4[gq0 + q] = sm;
            mean4[gq0 + q] = mv;
            var4 [gq0 + q] = vr;
        }
    }
}

extern "C" void kernel_launch(void* const* d_in, const int* in_sizes, int n_in,
                              void* d_out, int out_size, void* d_ws, size_t ws_size,
                              hipStream_t stream) {
    const float* b    = (const float*)d_in[0];
    // d_in[1] = labels (unused by the reference outputs)
    const float* Wmu  = (const float*)d_in[2];
    const float* bmu  = (const float*)d_in[3];
    const float* Wsig = (const float*)d_in[4];
    const float* bsig = (const float*)d_in[5];
    const float* eps  = (const float*)d_in[6];
    float* out = (float*)d_out;

    const size_t BH_BYTES = (size_t)B_ROWS * K_DIM * sizeof(__fp16); // 8 MB
    const dim3 grid(B_ROWS / ROWS_PER_BLOCK);  // 4096 blocks
    if (ws_size >= BH_BYTES) {
        __fp16* bhw = (__fp16*)d_ws;
        hipLaunchKernelGGL(pack_b_kernel, dim3(2048), dim3(256), 0, stream,
                           b, bhw);
        hipLaunchKernelGGL((sem_dec_kernel<1>), grid, dim3(THREADS), 0, stream,
                           b, bhw, Wmu, bmu, Wsig, bsig, eps, out);
    } else {
        hipLaunchKernelGGL((sem_dec_kernel<0>), grid, dim3(THREADS), 0, stream,
                           b, (const __fp16*)nullptr, Wmu, bmu, Wsig, bsig,
                           eps, out);
    }
}

// Round 11
// 81.856 us; speedup vs baseline: 1.7584x; 1.7584x over previous
//
#include <hip/hip_runtime.h>
#include <hip/hip_bf16.h>

// SemanticDecoder: mean = b@Wmu+bmu; s = b@Wsig+bsig; var = s*s;
// sample = mean + |s|*eps.  B=65536, K=64, D=300. f32 in/out.
// Outputs concatenated: [sample, mean, var], each B*D.
//
// R11: MFMA compute + LDS-staged linear writeout. R10 falsified the payload
// theory; the real binder was the VALU pipe: 2.52G MACs = 64-128us of dot2/
// fma issue across 256 CUs. MFMA does it in ~2.5us on the idle matrix pipe.
// R4 failed on scattered 4B C-stores; R8 on an HBM round-trip. Here the
// GEMM result (mean,s) is packed f16x2 into a 76.8KB LDS tile, and the
// epilogue streams eps-in / sample,mean,var-out as LINEAR float4
// (300 = 75 quads/row -> quad index linear over B*D).

#define B_ROWS 65536
#define K_DIM 64
#define D_DIM 300
#define NFRAG 19              // ceil(300/16)
#define ROWS_PER_BLOCK 64
#define THREADS 512           // 8 waves = 4 row-tiles x 2 col-halves
#define QPR 75                // float4-quads per row
#define QPB (ROWS_PER_BLOCK * QPR)  // 4800 quads per block

typedef __fp16 half2v __attribute__((ext_vector_type(2)));
typedef __fp16 half8v __attribute__((ext_vector_type(8)));
typedef float  f32x4  __attribute__((ext_vector_type(4)));

__device__ __forceinline__ half2v h2(unsigned int u) {
    return __builtin_bit_cast(half2v, u);
}
__device__ __forceinline__ unsigned int pkd(float a, float b) {
    return __builtin_bit_cast(unsigned int, __builtin_amdgcn_cvt_pkrtz(a, b));
}
__device__ __forceinline__ half8v pack8(float4 x, float4 y) {
    half2v p0 = __builtin_amdgcn_cvt_pkrtz(x.x, x.y);
    half2v p1 = __builtin_amdgcn_cvt_pkrtz(x.z, x.w);
    half2v p2 = __builtin_amdgcn_cvt_pkrtz(y.x, y.y);
    half2v p3 = __builtin_amdgcn_cvt_pkrtz(y.z, y.w);
    half8v r;
    r[0] = p0[0]; r[1] = p0[1]; r[2] = p1[0]; r[3] = p1[1];
    r[4] = p2[0]; r[5] = p2[1]; r[6] = p3[0]; r[7] = p3[1];
    return r;
}

// ---- kernel 0: pack W[64][300] f32 -> f16 MFMA B-fragments (d_ws) --------
// unit t = ((m*NFRAG + f)*2 + s)*64 + lane ; holds 8 f16:
//   W_m[k = s*32 + (lane>>4)*8 + e][col = f*16 + (lane&15)], e = 0..7
// (same k-permutation as the A-frag load below => cancels in the dot)
__global__ void pack_w_kernel(const float* __restrict__ Wmu,
                              const float* __restrict__ Wsig,
                              half8v* __restrict__ wpack)
{
    const int t = blockIdx.x * blockDim.x + threadIdx.x;
    const int total = 2 * NFRAG * 2 * 64;  // 4864
    if (t >= total) return;
    const int lane = t & 63;
    const int fs   = t >> 6;
    const int s    = fs & 1;
    const int mf   = fs >> 1;
    const int m    = mf / NFRAG;
    const int f    = mf - m * NFRAG;
    const int col  = f * 16 + (lane & 15);
    const int k0   = s * 32 + (lane >> 4) * 8;
    const float* W = m ? Wsig : Wmu;
    half8v o;
    #pragma unroll
    for (int e = 0; e < 8; ++e) {
        float v = (col < D_DIM) ? W[(size_t)(k0 + e) * D_DIM + col] : 0.f;
        o[e] = (__fp16)v;
    }
    wpack[t] = o;
}

// ---- main kernel ---------------------------------------------------------
__global__ __launch_bounds__(THREADS, 2) void sem_dec_main(
    const float* __restrict__ b,
    const float* __restrict__ bmu,
    const float* __restrict__ bsig,
    const float* __restrict__ eps,
    const half8v* __restrict__ wpack,
    float* __restrict__ out)
{
    __shared__ unsigned int lds_ms[ROWS_PER_BLOCK * D_DIM]; // 76.8 KB

    const int tid  = threadIdx.x;
    const int lane = tid & 63;
    const int wid  = tid >> 6;            // 0..7
    const int rt   = wid >> 1;            // row-tile 0..3
    const int ch   = wid & 1;             // col-half: frags 0-9 / 10-18
    const int row0 = blockIdx.x * ROWS_PER_BLOCK;

    // ---- A fragments (16 rows x 64 k): row = lane&15, k = (lane>>4)*8+e ----
    const int arow = lane & 15;
    const int kg   = lane >> 4;
    {
    }
    const float* bp = b + (size_t)(row0 + rt * 16 + arow) * K_DIM + kg * 8;
    float4 v0 = *reinterpret_cast<const float4*>(bp);
    float4 v1 = *reinterpret_cast<const float4*>(bp + 4);
    float4 v2 = *reinterpret_cast<const float4*>(bp + 32);
    float4 v3 = *reinterpret_cast<const float4*>(bp + 36);
    half8v a0 = pack8(v0, v1);   // k 0..31
    half8v a1 = pack8(v2, v3);   // k 32..63

    const int ccol = lane & 15;
    const int crow = (lane >> 4) * 4;     // + r (m89-verified C/D map)

    #pragma unroll
    for (int fi = 0; fi < 10; ++fi) {
        const int f = ch * 10 + fi;
        if (f >= NFRAG) break;            // ch=1, fi=9
        const int c = f * 16 + ccol;
        const bool cval = (c < D_DIM);
        // B fragments: coalesced 16B/lane loads from L2-hot wpack
        half8v wm0 = wpack[((0 * NFRAG + f) * 2 + 0) * 64 + lane];
        half8v wm1 = wpack[((0 * NFRAG + f) * 2 + 1) * 64 + lane];
        half8v ws0 = wpack[((1 * NFRAG + f) * 2 + 0) * 64 + lane];
        half8v ws1 = wpack[((1 * NFRAG + f) * 2 + 1) * 64 + lane];
        const float biasm = cval ? bmu[c] : 0.f;
        const float biass = cval ? bsig[c] : 0.f;
        f32x4 accm = {biasm, biasm, biasm, biasm};
        f32x4 accs = {biass, biass, biass, biass};
        accm = __builtin_amdgcn_mfma_f32_16x16x32_f16(a0, wm0, accm, 0, 0, 0);
        accm = __builtin_amdgcn_mfma_f32_16x16x32_f16(a1, wm1, accm, 0, 0, 0);
        accs = __builtin_amdgcn_mfma_f32_16x16x32_f16(a0, ws0, accs, 0, 0, 0);
        accs = __builtin_amdgcn_mfma_f32_16x16x32_f16(a1, ws1, accs, 0, 0, 0);
        if (cval) {
            #pragma unroll
            for (int r = 0; r < 4; ++r)   // 2-way bank alias only (free)
                lds_ms[(rt * 16 + crow + r) * D_DIM + c] = pkd(accm[r], accs[r]);
        }
    }
    __syncthreads();

    // ---- writeout: linear float4 streams over the block's 4800 quads ----
    const size_t BD  = (size_t)B_ROWS * D_DIM;
    const size_t gq0 = (size_t)row0 * QPR;
    const float4* eps4  = reinterpret_cast<const float4*>(eps);
    float4* samp4 = reinterpret_cast<float4*>(out);
    float4* mean4 = reinterpret_cast<float4*>(out + BD);
    float4* var4  = reinterpret_cast<float4*>(out + 2 * BD);
    for (int q = tid; q < QPB; q += THREADS) {
        const uint4 ms = reinterpret_cast<const uint4*>(lds_ms)[q];
        const float4 e = eps4[gq0 + q];
        const half2v p0 = h2(ms.x), p1 = h2(ms.y);
        const half2v p2 = h2(ms.z), p3 = h2(ms.w);
        float4 mv, sv;
        mv.x = (float)p0[0]; sv.x = (float)p0[1];
        mv.y = (float)p1[0]; sv.y = (float)p1[1];
        mv.z = (float)p2[0]; sv.z = (float)p2[1];
        mv.w = (float)p3[0]; sv.w = (float)p3[1];
        float4 sm, vr;
        sm.x = fmaf(fabsf(sv.x), e.x, mv.x);  vr.x = sv.x * sv.x;
        sm.y = fmaf(fabsf(sv.y), e.y, mv.y);  vr.y = sv.y * sv.y;
        sm.z = fmaf(fabsf(sv.z), e.z, mv.z);  vr.z = sv.z * sv.z;
        sm.w = fmaf(fabsf(sv.w), e.w, mv.w);  vr.w = sv.w * sv.w;
        samp4[gq0 + q] = sm;
        mean4[gq0 + q] = mv;
        var4 [gq0 + q] = vr;
    }
}

extern "C" void kernel_launch(void* const* d_in, const int* in_sizes, int n_in,
                              void* d_out, int out_size, void* d_ws, size_t ws_size,
                              hipStream_t stream) {
    const float* b    = (const float*)d_in[0];
    // d_in[1] = labels (unused by the reference outputs)
    const float* Wmu  = (const float*)d_in[2];
    const float* bmu  = (const float*)d_in[3];
    const float* Wsig = (const float*)d_in[4];
    const float* bsig = (const float*)d_in[5];
    const float* eps  = (const float*)d_in[6];
    float* out = (float*)d_out;
    half8v* wpack = (half8v*)d_ws;        // 4864 * 16 B = 77824 B

    hipLaunchKernelGGL(pack_w_kernel, dim3(19), dim3(256), 0, stream,
                       Wmu, Wsig, wpack);
    hipLaunchKernelGGL(sem_dec_main, dim3(B_ROWS / ROWS_PER_BLOCK),
                       dim3(THREADS), 0, stream,
                       b, bmu, bsig, eps, wpack, out);
}

// Round 12
// 73.005 us; speedup vs baseline: 1.9716x; 1.1212x over previous
//
#include <hip/hip_runtime.h>
#include <hip/hip_bf16.h>

// SemanticDecoder: mean = b@Wmu+bmu; s = b@Wsig+bsig; var = s*s;
// sample = mean + |s|*eps.  B=65536, K=64, D=300. f32 in/out.
// Outputs concatenated: [sample, mean, var], each B*D.
//
// R12 = R11 (MFMA + LDS-staged linear writeout, 82us WIN) + eps register
// prefetch: each thread issues its 10 epilogue eps quads as nontemporal
// loads at kernel entry -> HBM latency hides under the whole compute phase
// + barrier. Epilogue becomes pure {ds_read_b128, 12 FMA, 3x nt dwordx4
// store}. Nontemporal on streams keeps L2 clean for wpack B-frags.

#define B_ROWS 65536
#define K_DIM 64
#define D_DIM 300
#define NFRAG 19              // ceil(300/16)
#define ROWS_PER_BLOCK 64
#define THREADS 512           // 8 waves = 4 row-tiles x 2 col-halves
#define QPR 75                // float4-quads per row
#define QPB (ROWS_PER_BLOCK * QPR)  // 4800 quads per block
#define EPQ 10                // max eps quads per thread (4800/512 -> 9.375)

typedef __fp16 half2v __attribute__((ext_vector_type(2)));
typedef __fp16 half8v __attribute__((ext_vector_type(8)));
typedef float  f32x4  __attribute__((ext_vector_type(4)));
typedef unsigned int u32x4 __attribute__((ext_vector_type(4)));

__device__ __forceinline__ half2v h2(unsigned int u) {
    return __builtin_bit_cast(half2v, u);
}
__device__ __forceinline__ unsigned int pkd(float a, float b) {
    return __builtin_bit_cast(unsigned int, __builtin_amdgcn_cvt_pkrtz(a, b));
}
__device__ __forceinline__ half8v pack8(float4 x, float4 y) {
    half2v p0 = __builtin_amdgcn_cvt_pkrtz(x.x, x.y);
    half2v p1 = __builtin_amdgcn_cvt_pkrtz(x.z, x.w);
    half2v p2 = __builtin_amdgcn_cvt_pkrtz(y.x, y.y);
    half2v p3 = __builtin_amdgcn_cvt_pkrtz(y.z, y.w);
    half8v r;
    r[0] = p0[0]; r[1] = p0[1]; r[2] = p1[0]; r[3] = p1[1];
    r[4] = p2[0]; r[5] = p2[1]; r[6] = p3[0]; r[7] = p3[1];
    return r;
}

// ---- kernel 0: pack W[64][300] f32 -> f16 MFMA B-fragments (d_ws) --------
// unit t = ((m*NFRAG + f)*2 + s)*64 + lane ; holds 8 f16:
//   W_m[k = s*32 + (lane>>4)*8 + e][col = f*16 + (lane&15)], e = 0..7
// (same k-permutation as the A-frag load below => cancels in the dot)
__global__ void pack_w_kernel(const float* __restrict__ Wmu,
                              const float* __restrict__ Wsig,
                              half8v* __restrict__ wpack)
{
    const int t = blockIdx.x * blockDim.x + threadIdx.x;
    const int total = 2 * NFRAG * 2 * 64;  // 4864
    if (t >= total) return;
    const int lane = t & 63;
    const int fs   = t >> 6;
    const int s    = fs & 1;
    const int mf   = fs >> 1;
    const int m    = mf / NFRAG;
    const int f    = mf - m * NFRAG;
    const int col  = f * 16 + (lane & 15);
    const int k0   = s * 32 + (lane >> 4) * 8;
    const float* W = m ? Wsig : Wmu;
    half8v o;
    #pragma unroll
    for (int e = 0; e < 8; ++e) {
        float v = (col < D_DIM) ? W[(size_t)(k0 + e) * D_DIM + col] : 0.f;
        o[e] = (__fp16)v;
    }
    wpack[t] = o;
}

// ---- main kernel ---------------------------------------------------------
__global__ __launch_bounds__(THREADS, 2) void sem_dec_main(
    const float* __restrict__ b,
    const float* __restrict__ bmu,
    const float* __restrict__ bsig,
    const float* __restrict__ eps,
    const half8v* __restrict__ wpack,
    float* __restrict__ out)
{
    __shared__ unsigned int lds_ms[ROWS_PER_BLOCK * D_DIM]; // 76.8 KB

    const int tid  = threadIdx.x;
    const int lane = tid & 63;
    const int wid  = tid >> 6;            // 0..7
    const int rt   = wid >> 1;            // row-tile 0..3
    const int ch   = wid & 1;             // col-half: frags 0-9 / 10-18
    const int row0 = blockIdx.x * ROWS_PER_BLOCK;

    // ---- eps prefetch: issue ALL epilogue loads now (hide under compute) --
    const size_t gq0 = (size_t)row0 * QPR;
    const f32x4* eps4 = reinterpret_cast<const f32x4*>(eps);
    f32x4 epr[EPQ];
    #pragma unroll
    for (int i = 0; i < EPQ; ++i) {
        const int q = tid + i * THREADS;
        if (q < QPB) epr[i] = __builtin_nontemporal_load(&eps4[gq0 + q]);
    }

    // ---- A fragments (16 rows x 64 k): row = lane&15, k = (lane>>4)*8+e ----
    const int arow = lane & 15;
    const int kg   = lane >> 4;
    const float* bp = b + (size_t)(row0 + rt * 16 + arow) * K_DIM + kg * 8;
    float4 v0 = *reinterpret_cast<const float4*>(bp);
    float4 v1 = *reinterpret_cast<const float4*>(bp + 4);
    float4 v2 = *reinterpret_cast<const float4*>(bp + 32);
    float4 v3 = *reinterpret_cast<const float4*>(bp + 36);
    half8v a0 = pack8(v0, v1);   // k 0..31
    half8v a1 = pack8(v2, v3);   // k 32..63

    const int ccol = lane & 15;
    const int crow = (lane >> 4) * 4;     // + r (m89-verified C/D map)

    #pragma unroll
    for (int fi = 0; fi < 10; ++fi) {
        const int f = ch * 10 + fi;
        if (f >= NFRAG) break;            // ch=1, fi=9
        const int c = f * 16 + ccol;
        const bool cval = (c < D_DIM);
        // B fragments: coalesced 16B/lane loads from L2-hot wpack
        half8v wm0 = wpack[((0 * NFRAG + f) * 2 + 0) * 64 + lane];
        half8v wm1 = wpack[((0 * NFRAG + f) * 2 + 1) * 64 + lane];
        half8v ws0 = wpack[((1 * NFRAG + f) * 2 + 0) * 64 + lane];
        half8v ws1 = wpack[((1 * NFRAG + f) * 2 + 1) * 64 + lane];
        const float biasm = cval ? bmu[c] : 0.f;
        const float biass = cval ? bsig[c] : 0.f;
        f32x4 accm = {biasm, biasm, biasm, biasm};
        f32x4 accs = {biass, biass, biass, biass};
        accm = __builtin_amdgcn_mfma_f32_16x16x32_f16(a0, wm0, accm, 0, 0, 0);
        accm = __builtin_amdgcn_mfma_f32_16x16x32_f16(a1, wm1, accm, 0, 0, 0);
        accs = __builtin_amdgcn_mfma_f32_16x16x32_f16(a0, ws0, accs, 0, 0, 0);
        accs = __builtin_amdgcn_mfma_f32_16x16x32_f16(a1, ws1, accs, 0, 0, 0);
        if (cval) {
            #pragma unroll
            for (int r = 0; r < 4; ++r)   // 2-way bank alias only (free)
                lds_ms[(rt * 16 + crow + r) * D_DIM + c] = pkd(accm[r], accs[r]);
        }
    }
    __syncthreads();

    // ---- writeout: pure {ds_read_b128, FMA, 3x nt dwordx4 store} ----------
    const size_t BD = (size_t)B_ROWS * D_DIM;
    f32x4* samp4 = reinterpret_cast<f32x4*>(out);
    f32x4* mean4 = reinterpret_cast<f32x4*>(out + BD);
    f32x4* var4  = reinterpret_cast<f32x4*>(out + 2 * BD);
    const u32x4* lds4 = reinterpret_cast<const u32x4*>(lds_ms);
    #pragma unroll
    for (int i = 0; i < EPQ; ++i) {
        const int q = tid + i * THREADS;
        if (q < QPB) {
            const u32x4 ms = lds4[q];
            const f32x4 e = epr[i];
            const half2v p0 = h2(ms.x), p1 = h2(ms.y);
            const half2v p2 = h2(ms.z), p3 = h2(ms.w);
            f32x4 mv, sv, sm, vr;
            mv.x = (float)p0[0]; sv.x = (float)p0[1];
            mv.y = (float)p1[0]; sv.y = (float)p1[1];
            mv.z = (float)p2[0]; sv.z = (float)p2[1];
            mv.w = (float)p3[0]; sv.w = (float)p3[1];
            sm.x = fmaf(fabsf(sv.x), e.x, mv.x);  vr.x = sv.x * sv.x;
            sm.y = fmaf(fabsf(sv.y), e.y, mv.y);  vr.y = sv.y * sv.y;
            sm.z = fmaf(fabsf(sv.z), e.z, mv.z);  vr.z = sv.z * sv.z;
            sm.w = fmaf(fabsf(sv.w), e.w, mv.w);  vr.w = sv.w * sv.w;
            __builtin_nontemporal_store(sm, &samp4[gq0 + q]);
            __builtin_nontemporal_store(mv, &mean4[gq0 + q]);
            __builtin_nontemporal_store(vr, &var4[gq0 + q]);
        }
    }
}

extern "C" void kernel_launch(void* const* d_in, const int* in_sizes, int n_in,
                              void* d_out, int out_size, void* d_ws, size_t ws_size,
                              hipStream_t stream) {
    const float* b    = (const float*)d_in[0];
    // d_in[1] = labels (unused by the reference outputs)
    const float* Wmu  = (const float*)d_in[2];
    const float* bmu  = (const float*)d_in[3];
    const float* Wsig = (const float*)d_in[4];
    const float* bsig = (const float*)d_in[5];
    const float* eps  = (const float*)d_in[6];
    float* out = (float*)d_out;
    half8v* wpack = (half8v*)d_ws;        // 4864 * 16 B = 77824 B

    hipLaunchKernelGGL(pack_w_kernel, dim3(19), dim3(256), 0, stream,
                       Wmu, Wsig, wpack);
    hipLaunchKernelGGL(sem_dec_main, dim3(B_ROWS / ROWS_PER_BLOCK),
                       dim3(THREADS), 0, stream,
                       b, bmu, bsig, eps, wpack, out);
}